// Round 4
// baseline (202.684 us; speedup 1.0000x reference)
//
#include <hip/hip_runtime.h>

// IPUNeighborListMD — dense masked displacement matrix.
// out[m,i,j,c] = (pos[m,j,c] - pos[m,i,c]) * (|r_j - r_i|^2 < 49 && i != j)
// out: [64, 512, 512, 3] float32 (~201 MB) -> write-BW bound.
//
// R2: 220us (96B-stride stores). R3: +LDS transpose -> 194us; fills at
// 6.6 TB/s prove write path OK and kernel itself is ~73us (dur includes
// ~121us harness poison fill). R4: branch-free hot loop (dtype loads all
// hoisted to prologue) + nontemporal stores (kill potential L2 RFO).

#define NMOL   64
#define NATOM  512
#define RC2    49.0f      // (5.0 + 2.0)^2, exact in f32
#define SLICES 32         // blocks per molecule; each block does 16 rows

typedef unsigned int   u32;
typedef unsigned short u16;
typedef float f32x4 __attribute__((ext_vector_type(4)));

__device__ __forceinline__ float bf2f(u16 u) {
    union { u32 u; float f; } v; v.u = ((u32)u) << 16; return v.f;
}

__global__ __launch_bounds__(256)
void nbl_kernel(const void* __restrict__ pos_raw, float* __restrict__ out) {
    __shared__ float s_row[4][NATOM * 3];   // 6 KB per wave, wave-private
    __shared__ int s_f32;
    const int t = threadIdx.x;

    // ---- input dtype sniff (f32 vs packed bf16), block-uniform result ----
    if (t == 0) s_f32 = 0;
    __syncthreads();
    {
        const u32* w = (const u32*)pos_raw;
        const u32 a = w[t];
        const u32 b = w[t + 256];
        if ((((a >> 8) & 0xffu) > 0x41u) || (((b >> 8) & 0xffu) > 0x41u))
            s_f32 = 1;   // benign same-value race
    }
    __syncthreads();
    const bool is_f32 = (s_f32 != 0);

    const int bx     = blockIdx.x;
    const int m      = bx >> 5;                // molecule
    const int slice  = bx & (SLICES - 1);
    const int lane   = t & 63;
    const int wave   = t >> 6;
    const int i_base = slice * 16 + wave * 4;  // 4 waves x 4 rows = 16 rows

    const float* pm32 = (const float*)pos_raw + (size_t)m * (NATOM * 3);
    const u16*   pm16 = (const u16*)pos_raw   + (size_t)m * (NATOM * 3);

    // ---- prologue: ALL dtype-dependent loads happen here, once ----
    float pj[24];   // lane's 8 consecutive atoms j
    float ri[12];   // this wave's 4 row atoms i (wave-uniform)
    if (is_f32) {
        const float4* p4 = (const float4*)pm32 + lane * 6;   // 96 B / lane
        #pragma unroll
        for (int k = 0; k < 6; ++k) {
            const float4 q = p4[k];
            pj[4*k+0] = q.x; pj[4*k+1] = q.y; pj[4*k+2] = q.z; pj[4*k+3] = q.w;
        }
        #pragma unroll
        for (int r = 0; r < 4; ++r) {
            const int i = i_base + r;
            ri[3*r+0] = pm32[3*i+0];
            ri[3*r+1] = pm32[3*i+1];
            ri[3*r+2] = pm32[3*i+2];
        }
    } else {
        const uint4* p4 = (const uint4*)pm16 + lane * 3;     // 48 B / lane
        u32 words[12];
        #pragma unroll
        for (int k = 0; k < 3; ++k) {
            const uint4 q = p4[k];
            words[4*k+0] = q.x; words[4*k+1] = q.y;
            words[4*k+2] = q.z; words[4*k+3] = q.w;
        }
        #pragma unroll
        for (int k = 0; k < 12; ++k) {
            pj[2*k]   = bf2f((u16)(words[k] & 0xffffu));
            pj[2*k+1] = bf2f((u16)(words[k] >> 16));
        }
        #pragma unroll
        for (int r = 0; r < 4; ++r) {
            const int i = i_base + r;
            ri[3*r+0] = bf2f(pm16[3*i+0]);
            ri[3*r+1] = bf2f(pm16[3*i+1]);
            ri[3*r+2] = bf2f(pm16[3*i+2]);
        }
    }

    const int j0 = lane * 8;
    float* sw = s_row[wave];

    // ---- branch-free hot loop ----
    #pragma unroll
    for (int r = 0; r < 4; ++r) {
        const int i = i_base + r;
        const float rix = ri[3*r+0], riy = ri[3*r+1], riz = ri[3*r+2];

        float o[24];
        #pragma unroll
        for (int jj = 0; jj < 8; ++jj) {
            // Exact numpy f32 semantics: rounded sub/mul, sequential rounded
            // adds ((x+y)+z), NO fma contraction (cutoff-boundary mask!).
            const float dx = __fsub_rn(pj[3*jj+0], rix);
            const float dy = __fsub_rn(pj[3*jj+1], riy);
            const float dz = __fsub_rn(pj[3*jj+2], riz);
            const float d2 = __fadd_rn(__fadd_rn(__fmul_rn(dx, dx),
                                                 __fmul_rn(dy, dy)),
                                       __fmul_rn(dz, dz));
            const bool keep = (d2 < RC2) && ((j0 + jj) != i);
            o[3*jj+0] = keep ? dx : 0.0f;
            o[3*jj+1] = keep ? dy : 0.0f;
            o[3*jj+2] = keep ? dz : 0.0f;
        }

        // wave-local transpose through LDS (in-order ds ops, no barrier)
        float4* wp = (float4*)(sw + lane * 24);      // 96 B aligned
        #pragma unroll
        for (int k = 0; k < 6; ++k)
            wp[k] = make_float4(o[4*k+0], o[4*k+1], o[4*k+2], o[4*k+3]);

        // Coalesced nontemporal global stores: lane stride 16 B.
        const size_t row = (size_t)(m * NATOM + i);
        f32x4* ob = (f32x4*)out + row * 384;
        const f32x4* sr = (const f32x4*)sw;
        #pragma unroll
        for (int k = 0; k < 6; ++k)
            __builtin_nontemporal_store(sr[k * 64 + lane], &ob[k * 64 + lane]);
    }
}

extern "C" void kernel_launch(void* const* d_in, const int* in_sizes, int n_in,
                              void* d_out, int out_size, void* d_ws, size_t ws_size,
                              hipStream_t stream) {
    const void* pos = d_in[0];
    float* out = (float*)d_out;
    dim3 grid(NMOL * SLICES);   // 2048 blocks
    dim3 block(256);
    nbl_kernel<<<grid, block, 0, stream>>>(pos, out);
}

// Round 5
// 193.446 us; speedup vs baseline: 1.0478x; 1.0478x over previous
//
#include <hip/hip_runtime.h>

// IPUNeighborListMD — dense masked displacement matrix.
// out[m,i,j,c] = (pos[m,j,c] - pos[m,i,c]) * (|r_j - r_i|^2 < 49 && i != j)
// out: [64, 512, 512, 3] f32 (192 MiB) -> write-BW bound (~30 us floor).
//
// Key identity: out[m,i,f] = (pos_flat[m,f] - r_i[f%3]) * keep[f/3].
// pos_flat is already in output order -> no 6 KB/row LDS transpose; only the
// 512-float keep vector (atom-major produced, f-major consumed) goes through
// LDS (2 KB/wave). Stores are register-sourced, 16 B lane stride.
// dur_us includes a ~120 us harness poison fill; kernel itself is the rest.

#define NMOL   64
#define NATOM  512
#define RC2    49.0f      // (5.0 + 2.0)^2, exact in f32
#define SLICES 64         // blocks per molecule; 8 rows/block, 2 rows/wave

typedef unsigned int   u32;
typedef unsigned short u16;

__device__ __forceinline__ float bf2f(u16 u) {
    union { u32 u; float f; } v; v.u = ((u32)u) << 16; return v.f;
}

__global__ __launch_bounds__(256)
void nbl_kernel(const void* __restrict__ pos_raw, float* __restrict__ out) {
    __shared__ float s_keep[4][NATOM];   // per-wave keep vector, 2 KB each
    __shared__ int s_f32;
    const int t = threadIdx.x;

    // ---- input dtype sniff (f32 vs packed bf16), block-uniform result ----
    if (t == 0) s_f32 = 0;
    __syncthreads();
    {
        const u32* w = (const u32*)pos_raw;
        const u32 a = w[t];
        const u32 b = w[t + 256];
        if ((((a >> 8) & 0xffu) > 0x41u) || (((b >> 8) & 0xffu) > 0x41u))
            s_f32 = 1;   // benign same-value race
    }
    __syncthreads();
    const bool is_f32 = (s_f32 != 0);

    const int bx     = blockIdx.x;
    const int m      = bx >> 6;                 // molecule
    const int slice  = bx & (SLICES - 1);
    const int lane   = t & 63;
    const int wave   = t >> 6;
    const int i_base = slice * 8 + wave * 2;    // 4 waves x 2 rows = 8 rows

    const float* pm32 = (const float*)pos_raw + (size_t)m * (NATOM * 3);
    const u16*   pm16 = (const u16*)pos_raw   + (size_t)m * (NATOM * 3);

    // ---- prologue: all global loads, both dtype paths ----
    float pj[24];   // lane's 8 consecutive atoms j (phase-1 d2 source)
    float pc[24];   // lane's 6 output chunks c=64k+lane (phase-2 store source)
    float ri[6];    // this wave's 2 row atoms (wave-uniform)
    if (is_f32) {
        const float4* p4 = (const float4*)pm32 + lane * 6;
        #pragma unroll
        for (int k = 0; k < 6; ++k) {
            const float4 q = p4[k];
            pj[4*k+0] = q.x; pj[4*k+1] = q.y; pj[4*k+2] = q.z; pj[4*k+3] = q.w;
        }
        const float4* c4 = (const float4*)pm32;
        #pragma unroll
        for (int k = 0; k < 6; ++k) {
            const float4 q = c4[64*k + lane];
            pc[4*k+0] = q.x; pc[4*k+1] = q.y; pc[4*k+2] = q.z; pc[4*k+3] = q.w;
        }
        #pragma unroll
        for (int r = 0; r < 2; ++r) {
            const int i = i_base + r;
            ri[3*r+0] = pm32[3*i+0]; ri[3*r+1] = pm32[3*i+1]; ri[3*r+2] = pm32[3*i+2];
        }
    } else {
        const uint4* p4 = (const uint4*)pm16 + lane * 3;
        u32 words[12];
        #pragma unroll
        for (int k = 0; k < 3; ++k) {
            const uint4 q = p4[k];
            words[4*k+0] = q.x; words[4*k+1] = q.y;
            words[4*k+2] = q.z; words[4*k+3] = q.w;
        }
        #pragma unroll
        for (int k = 0; k < 12; ++k) {
            pj[2*k]   = bf2f((u16)(words[k] & 0xffffu));
            pj[2*k+1] = bf2f((u16)(words[k] >> 16));
        }
        const uint2* c2 = (const uint2*)pm16;
        #pragma unroll
        for (int k = 0; k < 6; ++k) {
            const uint2 q = c2[64*k + lane];
            pc[4*k+0] = bf2f((u16)(q.x & 0xffffu));
            pc[4*k+1] = bf2f((u16)(q.x >> 16));
            pc[4*k+2] = bf2f((u16)(q.y & 0xffffu));
            pc[4*k+3] = bf2f((u16)(q.y >> 16));
        }
        #pragma unroll
        for (int r = 0; r < 2; ++r) {
            const int i = i_base + r;
            ri[3*r+0] = bf2f(pm16[3*i+0]);
            ri[3*r+1] = bf2f(pm16[3*i+1]);
            ri[3*r+2] = bf2f(pm16[3*i+2]);
        }
    }

    // row-invariant chunk indexing: c = 64k+lane, cm = c%3, ja = floor(4c/3)
    int cms[6], jas[6];
    #pragma unroll
    for (int k = 0; k < 6; ++k) {
        const int c = 64 * k + lane;
        cms[k] = c % 3;
        jas[k] = (4 * c) / 3;     // compiler magic-mul
    }

    const int j0 = lane * 8;
    float* kw = s_keep[wave];

    #pragma unroll
    for (int r = 0; r < 2; ++r) {
        const int i = i_base + r;
        const float rx = ri[3*r+0], ry = ri[3*r+1], rz = ri[3*r+2];

        // ---- phase 1: keep[j] for lane's 8 atoms, atom-major ----
        float kv[8];
        #pragma unroll
        for (int jj = 0; jj < 8; ++jj) {
            // Exact numpy f32 semantics: rounded sub/mul, sequential rounded
            // adds ((x+y)+z), NO fma contraction (cutoff-boundary mask!).
            const float dx = __fsub_rn(pj[3*jj+0], rx);
            const float dy = __fsub_rn(pj[3*jj+1], ry);
            const float dz = __fsub_rn(pj[3*jj+2], rz);
            const float d2 = __fadd_rn(__fadd_rn(__fmul_rn(dx, dx),
                                                 __fmul_rn(dy, dy)),
                                       __fmul_rn(dz, dz));
            kv[jj] = ((d2 < RC2) && ((j0 + jj) != i)) ? 1.0f : 0.0f;
        }
        float4* kw4 = (float4*)(kw + j0);
        kw4[0] = make_float4(kv[0], kv[1], kv[2], kv[3]);
        kw4[1] = make_float4(kv[4], kv[5], kv[6], kv[7]);
        // same-wave ds ordering: writes complete before reads below (lgkmcnt)

        // ---- phase 2: f-major stores straight from registers ----
        const size_t row = (size_t)(m * NATOM + i);
        float4* ob = (float4*)out + row * 384;
        #pragma unroll
        for (int k = 0; k < 6; ++k) {
            const int cm = cms[k];
            const int ja = jas[k];
            const float ka = kw[ja];        // ds_read2_b32 pair
            const float kb = kw[ja + 1];
            // comps(t) = (c+t)%3 ; j bumps a->b when cm+t >= 3
            const float r0 = (cm == 0) ? rx : ((cm == 1) ? ry : rz);
            const float r1 = (cm == 0) ? ry : ((cm == 1) ? rz : rx);
            const float r2 = (cm == 0) ? rz : ((cm == 1) ? rx : ry);
            const float m0 = ka;
            const float m1 = (cm == 2) ? kb : ka;
            const float m2 = (cm == 0) ? ka : kb;
            const float m3 = kb;
            float4 o;
            o.x = __fmul_rn(__fsub_rn(pc[4*k+0], r0), m0);
            o.y = __fmul_rn(__fsub_rn(pc[4*k+1], r1), m1);
            o.z = __fmul_rn(__fsub_rn(pc[4*k+2], r2), m2);
            o.w = __fmul_rn(__fsub_rn(pc[4*k+3], r0), m3);
            ob[64 * k + lane] = o;
        }
    }
}

extern "C" void kernel_launch(void* const* d_in, const int* in_sizes, int n_in,
                              void* d_out, int out_size, void* d_ws, size_t ws_size,
                              hipStream_t stream) {
    const void* pos = d_in[0];
    float* out = (float*)d_out;
    dim3 grid(NMOL * SLICES);   // 4096 blocks
    dim3 block(256);
    nbl_kernel<<<grid, block, 0, stream>>>(pos, out);
}